// Round 1
// baseline (539.918 us; speedup 1.0000x reference)
//
#include <hip/hip_runtime.h>
#include <math.h>

// SS2D wrapper: conv1x1+BN+PReLU -> conv3x3+BN+PReLU -> SS2D(4-dir selective
// scan) -> gamma*ss + residual.  All fp32.  B=1, C=96, H=W=48, DI=192, N=16,
// R=6, K=4, L=2304.  Scan parallelized via 24-chunk 3-phase decomposition.

namespace {

constexpr int LT   = 2304;  // H*W
constexpr int HWD  = 48;
constexpr int CCH  = 96;
constexpr int DIM  = 192;
constexpr int NST  = 16;
constexpr int NRK  = 6;     // R
constexpr int NCHK = 24;    // chunks over L
constexpr int LCHK = 96;    // chunk length (NCHK*LCHK == LT)

__device__ __forceinline__ float silu_f(float v) { return v / (1.f + __expf(-v)); }
__device__ __forceinline__ float softplus_f(float v) {
  return (v > 20.f) ? v : log1pf(__expf(v));
}
// spatial pixel visited at scan-step l of direction k
//  k0: row-major fwd; k1: col-major fwd; k2: row-major rev; k3: col-major rev
__device__ __forceinline__ int scan_pix(int k, int l) {
  int ll = (k & 2) ? (LT - 1 - l) : l;
  return (k & 1) ? ((ll % HWD) * HWD + (ll / HWD)) : ll;
}

// A[k,d,n] = -exp(A_logs)
__global__ void __launch_bounds__(256) k_abuf(const float* __restrict__ alog,
                                              float* __restrict__ ab) {
  int id = blockIdx.x * 256 + threadIdx.x;  // 12288
  ab[id] = -__expf(alog[id]);
}

// 1x1 conv + BN + PReLU
__global__ void __launch_bounds__(256) k_conv0(
    const float* __restrict__ x, const float* __restrict__ wt,
    const float* __restrict__ bw, const float* __restrict__ bb,
    const float* __restrict__ bm, const float* __restrict__ bv,
    const float* __restrict__ pr, float* __restrict__ out) {
  int id = blockIdx.x * 256 + threadIdx.x;  // 96*2304
  int p = id % LT, co = id / LT;
  float acc = 0.f;
  const float* wr = wt + co * CCH;
  for (int ci = 0; ci < CCH; ++ci) acc = fmaf(wr[ci], x[ci * LT + p], acc);
  float s = bw[co] * rsqrtf(bv[co] + 1e-5f);
  float y = (acc - bm[co]) * s + bb[co];
  out[id] = y > 0.f ? y : pr[co] * y;
}

// 3x3 conv (pad 1) + BN + PReLU, 4 output channels per thread
__global__ void __launch_bounds__(256) k_conv1(
    const float* __restrict__ in, const float* __restrict__ wt,
    const float* __restrict__ bw, const float* __restrict__ bb,
    const float* __restrict__ bm, const float* __restrict__ bv,
    const float* __restrict__ pr, float* __restrict__ out) {
  int id = blockIdx.x * 256 + threadIdx.x;  // 24*2304
  int p = id % LT, c0 = id / LT;
  int py = p / HWD, px = p % HWD;
  float a0 = 0.f, a1 = 0.f, a2 = 0.f, a3 = 0.f;
  for (int ci = 0; ci < CCH; ++ci) {
    const float* ip = in + ci * LT;
    #pragma unroll
    for (int dy = -1; dy <= 1; ++dy) {
      int yy = py + dy;
      if (yy < 0 || yy >= HWD) continue;
      #pragma unroll
      for (int dx = -1; dx <= 1; ++dx) {
        int xx2 = px + dx;
        if (xx2 < 0 || xx2 >= HWD) continue;
        float v = ip[yy * HWD + xx2];
        int wb = (ci * 3 + (dy + 1)) * 3 + (dx + 1);
        a0 = fmaf(wt[(c0     ) * CCH * 9 + wb], v, a0);
        a1 = fmaf(wt[(c0 + 24) * CCH * 9 + wb], v, a1);
        a2 = fmaf(wt[(c0 + 48) * CCH * 9 + wb], v, a2);
        a3 = fmaf(wt[(c0 + 72) * CCH * 9 + wb], v, a3);
      }
    }
  }
  float acc[4] = {a0, a1, a2, a3};
  #pragma unroll
  for (int j = 0; j < 4; ++j) {
    int co = c0 + j * 24;
    float s = bw[co] * rsqrtf(bv[co] + 1e-5f);
    float y = (acc[j] - bm[co]) * s + bb[co];
    out[co * LT + p] = y > 0.f ? y : pr[co] * y;
  }
}

// in_proj: xz[e][p] = sum_c W[e][c]*in[c][p]; e<192 -> xx[d][p], e>=192 -> silu(z)[p][d]
__global__ void __launch_bounds__(256) k_inproj(
    const float* __restrict__ in, const float* __restrict__ wt,
    float* __restrict__ xx, float* __restrict__ zsil) {
  int id = blockIdx.x * 256 + threadIdx.x;  // 96*2304
  int p = id % LT, e0 = id / LT;
  float a0 = 0.f, a1 = 0.f, a2 = 0.f, a3 = 0.f;
  for (int c = 0; c < CCH; ++c) {
    float v = in[c * LT + p];
    a0 = fmaf(wt[(e0      ) * CCH + c], v, a0);
    a1 = fmaf(wt[(e0 +  96) * CCH + c], v, a1);
    a2 = fmaf(wt[(e0 + 192) * CCH + c], v, a2);
    a3 = fmaf(wt[(e0 + 288) * CCH + c], v, a3);
  }
  xx[e0 * LT + p]        = a0;
  xx[(e0 + 96) * LT + p] = a1;
  zsil[p * DIM + e0]      = silu_f(a2);
  zsil[p * DIM + e0 + 96] = silu_f(a3);
}

// depthwise 3x3 + bias + SiLU
__global__ void __launch_bounds__(256) k_dwconv(
    const float* __restrict__ xx, const float* __restrict__ wt,
    const float* __restrict__ bias, float* __restrict__ xc) {
  int id = blockIdx.x * 256 + threadIdx.x;  // 192*2304
  int p = id % LT, d = id / LT;
  int py = p / HWD, px = p % HWD;
  float acc = bias[d];
  const float* ip = xx + d * LT;
  #pragma unroll
  for (int dy = -1; dy <= 1; ++dy) {
    int yy = py + dy;
    if (yy < 0 || yy >= HWD) continue;
    #pragma unroll
    for (int dx = -1; dx <= 1; ++dx) {
      int xx2 = px + dx;
      if (xx2 < 0 || xx2 >= HWD) continue;
      acc = fmaf(wt[d * 9 + (dy + 1) * 3 + (dx + 1)], ip[yy * HWD + xx2], acc);
    }
  }
  xc[d * LT + p] = silu_f(acc);
}

// x_dbl[k][l][0..37] = sum_d xc[d][p_k(l)] * xw[k][c][d]   (38 accumulators)
// fused: dtbuf[k][d][l] = softplus(sum_r x_dbl[k][l][r]*dtw[k][d][r] + dtb[k][d])
__global__ void __launch_bounds__(64) k_xdbl_dt(
    const float* __restrict__ xc, const float* __restrict__ xw,
    const float* __restrict__ dtw, const float* __restrict__ dtb,
    float* __restrict__ xdbl, float* __restrict__ dtbuf) {
  int id = blockIdx.x * 64 + threadIdx.x;  // 4*2304
  int l = id % LT, k = id / LT;
  int p = scan_pix(k, l);
  float acc[38];
  #pragma unroll
  for (int c = 0; c < 38; ++c) acc[c] = 0.f;
  const float* wk = xw + k * 38 * DIM;
  for (int d = 0; d < DIM; ++d) {
    float v = xc[d * LT + p];
    #pragma unroll
    for (int c = 0; c < 38; ++c) acc[c] = fmaf(wk[c * DIM + d], v, acc[c]);
  }
  float* o = xdbl + (k * LT + l) * 38;
  #pragma unroll
  for (int c = 0; c < 38; ++c) o[c] = acc[c];
  // dt projection + softplus for all 192 channels of this (k,l)
  for (int d = 0; d < DIM; ++d) {
    const float* wp = dtw + (k * DIM + d) * NRK;
    float a = dtb[k * DIM + d];
    a = fmaf(wp[0], acc[0], a);
    a = fmaf(wp[1], acc[1], a);
    a = fmaf(wp[2], acc[2], a);
    a = fmaf(wp[3], acc[3], a);
    a = fmaf(wp[4], acc[4], a);
    a = fmaf(wp[5], acc[5], a);
    dtbuf[(k * DIM + d) * LT + l] = softplus_f(a);
  }
}

// Phase A: per-(k,d,chunk) local scan from h=0.  16 lanes = 16 states.
// Writes y_local (incl. D*x) to yloc[k][l][d], cumulative dt to cumdt[k][l][d],
// and the chunk-final h to hend.
__global__ void __launch_bounds__(256) k_scanA(
    const float* __restrict__ dtbuf, const float* __restrict__ xc,
    const float* __restrict__ xdbl, const float* __restrict__ Abuf,
    const float* __restrict__ Ds, float* __restrict__ yloc,
    float* __restrict__ cumdt, float* __restrict__ hend) {
  int tid = threadIdx.x;
  int g = blockIdx.x * 16 + (tid >> 4);  // 18432 groups
  int n = tid & 15;
  int c = g % NCHK;
  int t = g / NCHK;
  int d = t % DIM, k = t / DIM;
  float An = Abuf[(k * DIM + d) * NST + n];
  float Dv = Ds[k * DIM + d];
  const float* dtp = dtbuf + (k * DIM + d) * LT;
  const float* xcp = xc + d * LT;
  float h = 0.f, cum = 0.f;
  int l0 = c * LCHK;
  for (int i = 0; i < LCHK; ++i) {
    int l = l0 + i;
    float dt = dtp[l];
    cum += dt;
    float xv = xcp[scan_pix(k, l)];
    const float* row = xdbl + (k * LT + l) * 38;
    float a = __expf(dt * An);
    h = fmaf(h, a, dt * row[6 + n] * xv);
    float part = h * row[22 + n];
    part += __shfl_xor(part, 1, 16);
    part += __shfl_xor(part, 2, 16);
    part += __shfl_xor(part, 4, 16);
    part += __shfl_xor(part, 8, 16);
    if (n == 0) {
      yloc [(k * LT + l) * DIM + d] = part + Dv * xv;
      cumdt[(k * LT + l) * DIM + d] = cum;
    }
  }
  hend[g * NST + n] = h;
}

// Phase B: sequential stitch of chunk summaries -> hin (incoming h per chunk)
__global__ void __launch_bounds__(256) k_scanB(
    const float* __restrict__ cumdt, const float* __restrict__ hend,
    const float* __restrict__ Abuf, float* __restrict__ hin) {
  int id = blockIdx.x * 256 + threadIdx.x;  // 12288 = (k,d,n)
  int n = id & 15;
  int kd = id >> 4;
  int d = kd % DIM, k = kd / DIM;
  (void)n;
  float An = Abuf[id];
  float carry = 0.f;
  for (int c = 0; c < NCHK; ++c) {
    int base = (kd * NCHK + c) * NST + (id & 15);
    hin[base] = carry;
    float dtsum = cumdt[(k * LT + c * LCHK + (LCHK - 1)) * DIM + d];
    carry = __expf(An * dtsum) * carry + hend[base];
  }
}

// Phase C: y += sum_n hin[n] * exp(A_n * cumdt) * C_n
__global__ void __launch_bounds__(256) k_scanC(
    const float* __restrict__ cumdt, const float* __restrict__ hin,
    const float* __restrict__ Abuf, const float* __restrict__ xdbl,
    float* __restrict__ yloc) {
  int id = blockIdx.x * 256 + threadIdx.x;  // 4*2304*192, d fastest
  int d = id % DIM;
  int t = id / DIM;
  int l = t % LT, k = t / LT;
  int c = l / LCHK;
  if (c == 0) return;  // hin == 0 for first chunk
  int idx = (k * LT + l) * DIM + d;
  float cum = cumdt[idx];
  int kd = k * DIM + d;
  const float* hp = hin + (kd * NCHK + c) * NST;
  const float* Ap = Abuf + kd * NST;
  const float* Cp = xdbl + (k * LT + l) * 38 + 22;
  float corr = 0.f;
  #pragma unroll
  for (int n = 0; n < NST; ++n)
    corr = fmaf(hp[n] * __expf(Ap[n] * cum), Cp[n], corr);
  yloc[idx] += corr;
}

// Combine 4 directions (gather per direction-mapping), LayerNorm over DI,
// multiply by silu(z); one wave per pixel, 3 channels per lane.
__global__ void __launch_bounds__(64) k_lncomb(
    const float* __restrict__ yloc, const float* __restrict__ zsil,
    const float* __restrict__ nw, const float* __restrict__ nb,
    float* __restrict__ ynorm) {
  int p = blockIdx.x;
  int lane = threadIdx.x;
  int l1 = (p % HWD) * HWD + p / HWD;
  int l0 = p, l2 = LT - 1 - p, l3 = LT - 1 - l1;
  float vs[3];
  #pragma unroll
  for (int j = 0; j < 3; ++j) {
    int d = lane + j * 64;
    vs[j] = yloc[(0 * LT + l0) * DIM + d]
          + yloc[(1 * LT + l1) * DIM + d]
          + yloc[(2 * LT + l2) * DIM + d]
          + yloc[(3 * LT + l3) * DIM + d];
  }
  float s = vs[0] + vs[1] + vs[2];
  #pragma unroll
  for (int m = 1; m < 64; m <<= 1) s += __shfl_xor(s, m, 64);
  float mu = s * (1.f / DIM);
  float s2 = 0.f;
  #pragma unroll
  for (int j = 0; j < 3; ++j) { float tv = vs[j] - mu; s2 = fmaf(tv, tv, s2); }
  #pragma unroll
  for (int m = 1; m < 64; m <<= 1) s2 += __shfl_xor(s2, m, 64);
  float inv = rsqrtf(s2 * (1.f / DIM) + 1e-5f);
  #pragma unroll
  for (int j = 0; j < 3; ++j) {
    int d = lane + j * 64;
    float yn = (vs[j] - mu) * inv * nw[d] + nb[d];
    ynorm[p * DIM + d] = yn * zsil[p * DIM + d];
  }
}

// out_proj + gamma*ss + residual, 4 output channels per thread
__global__ void __launch_bounds__(256) k_out(
    const float* __restrict__ ynorm, const float* __restrict__ opw,
    const float* __restrict__ res, const float* __restrict__ gamma,
    float* __restrict__ out) {
  int id = blockIdx.x * 256 + threadIdx.x;  // 24*2304
  int p = id % LT, c0 = id / LT;
  const float* yp = ynorm + p * DIM;
  float a0 = 0.f, a1 = 0.f, a2 = 0.f, a3 = 0.f;
  for (int d = 0; d < DIM; ++d) {
    float v = yp[d];
    a0 = fmaf(opw[(c0     ) * DIM + d], v, a0);
    a1 = fmaf(opw[(c0 + 24) * DIM + d], v, a1);
    a2 = fmaf(opw[(c0 + 48) * DIM + d], v, a2);
    a3 = fmaf(opw[(c0 + 72) * DIM + d], v, a3);
  }
  float g = gamma[0];
  out[(c0     ) * LT + p] = fmaf(g, a0, res[(c0     ) * LT + p]);
  out[(c0 + 24) * LT + p] = fmaf(g, a1, res[(c0 + 24) * LT + p]);
  out[(c0 + 48) * LT + p] = fmaf(g, a2, res[(c0 + 48) * LT + p]);
  out[(c0 + 72) * LT + p] = fmaf(g, a3, res[(c0 + 72) * LT + p]);
}

}  // namespace

extern "C" void kernel_launch(void* const* d_in, const int* in_sizes, int n_in,
                              void* d_out, int out_size, void* d_ws, size_t ws_size,
                              hipStream_t stream) {
  (void)in_sizes; (void)n_in; (void)out_size; (void)ws_size;
  const float* x    = (const float*)d_in[0];
  const float* c0w  = (const float*)d_in[1];
  const float* bn0w = (const float*)d_in[2];
  const float* bn0b = (const float*)d_in[3];
  const float* bn0m = (const float*)d_in[4];
  const float* bn0v = (const float*)d_in[5];
  const float* pr0  = (const float*)d_in[6];
  const float* c1w  = (const float*)d_in[7];
  const float* bn1w = (const float*)d_in[8];
  const float* bn1b = (const float*)d_in[9];
  const float* bn1m = (const float*)d_in[10];
  const float* bn1v = (const float*)d_in[11];
  const float* pr1  = (const float*)d_in[12];
  const float* ipw  = (const float*)d_in[13];
  const float* dww  = (const float*)d_in[14];
  const float* dwb  = (const float*)d_in[15];
  const float* xpw  = (const float*)d_in[16];
  const float* dtw  = (const float*)d_in[17];
  const float* dtb  = (const float*)d_in[18];
  const float* alog = (const float*)d_in[19];
  const float* Dsp  = (const float*)d_in[20];
  const float* onw  = (const float*)d_in[21];
  const float* onb  = (const float*)d_in[22];
  const float* opw  = (const float*)d_in[23];
  const float* gam  = (const float*)d_in[24];
  float* out = (float*)d_out;

  // workspace carve (floats); total ~8.47M floats = 33.9 MB
  float* ws    = (float*)d_ws;
  float* out0  = ws;                 // 96*2304
  float* out1  = out0  + 221184;     // 96*2304
  float* xxb   = out1  + 221184;     // 192*2304
  float* zsil  = xxb   + 442368;     // 2304*192
  float* xcb   = zsil  + 442368;     // 192*2304
  float* xdbl  = xcb   + 442368;     // 4*2304*38
  float* dtbuf = xdbl  + 350208;     // 4*192*2304
  float* cumdt = dtbuf + 1769472;    // 4*2304*192
  float* yloc  = cumdt + 1769472;    // 4*2304*192
  float* hend  = yloc  + 1769472;    // 4*192*24*16
  float* hin   = hend  + 294912;     // 4*192*24*16
  float* Abuf  = hin   + 294912;     // 4*192*16
  float* ynorm = Abuf  + 12288;      // 2304*192

  k_abuf  <<<  48, 256, 0, stream>>>(alog, Abuf);
  k_conv0 <<< 864, 256, 0, stream>>>(x, c0w, bn0w, bn0b, bn0m, bn0v, pr0, out0);
  k_conv1 <<< 216, 256, 0, stream>>>(out0, c1w, bn1w, bn1b, bn1m, bn1v, pr1, out1);
  k_inproj<<< 864, 256, 0, stream>>>(out1, ipw, xxb, zsil);
  k_dwconv<<<1728, 256, 0, stream>>>(xxb, dww, dwb, xcb);
  k_xdbl_dt<<<144,  64, 0, stream>>>(xcb, xpw, dtw, dtb, xdbl, dtbuf);
  k_scanA <<<1152, 256, 0, stream>>>(dtbuf, xcb, xdbl, Abuf, Dsp, yloc, cumdt, hend);
  k_scanB <<<  48, 256, 0, stream>>>(cumdt, hend, Abuf, hin);
  k_scanC <<<6912, 256, 0, stream>>>(cumdt, hin, Abuf, xdbl, yloc);
  k_lncomb<<<2304,  64, 0, stream>>>(yloc, zsil, onw, onb, ynorm);
  k_out   <<< 216, 256, 0, stream>>>(ynorm, opw, out1, gam, out);
}

// Round 2
// 397.730 us; speedup vs baseline: 1.3575x; 1.3575x over previous
//
#include <hip/hip_runtime.h>
#include <math.h>

// SS2D wrapper: conv1x1+BN+PReLU -> conv3x3+BN+PReLU -> SS2D(4-dir selective
// scan) -> gamma*ss + residual.  All fp32.  B=1, C=96, H=W=48, DI=192, N=16,
// R=6, K=4, L=2304.  Scan parallelized via 24-chunk 3-phase decomposition.
// R1: x_dbl/dt restructured output-parallel (was 1.5% occupancy, 170us);
//     xcT transposed copy for coalesced col-major loads; scanB/C layouts
//     reordered d-innermost for coalescing.

namespace {

constexpr int LT   = 2304;  // H*W
constexpr int HWD  = 48;
constexpr int CCH  = 96;
constexpr int DIM  = 192;
constexpr int NST  = 16;
constexpr int NCHK = 24;    // chunks over L
constexpr int LCHK = 96;    // chunk length (NCHK*LCHK == LT)

__device__ __forceinline__ float silu_f(float v) { return v / (1.f + __expf(-v)); }
__device__ __forceinline__ float softplus_f(float v) {
  return (v > 20.f) ? v : log1pf(__expf(v));
}

// A[k,d,n] = -exp(A_logs); writes two layouts:
//   Abuf[(k*DIM+d)*NST+n]  (scanA: lane-n consecutive)
//   A2  [(k*NST+n)*DIM+d]  (scanB/C: lane-d consecutive)
__global__ void __launch_bounds__(256) k_abuf(const float* __restrict__ alog,
                                              float* __restrict__ ab,
                                              float* __restrict__ a2) {
  int id = blockIdx.x * 256 + threadIdx.x;  // 12288
  float v = -__expf(alog[id]);
  ab[id] = v;
  int n = id & 15;
  int kd = id >> 4;
  int d = kd % DIM, k = kd / DIM;
  a2[(k * NST + n) * DIM + d] = v;
}

// 1x1 conv + BN + PReLU
__global__ void __launch_bounds__(256) k_conv0(
    const float* __restrict__ x, const float* __restrict__ wt,
    const float* __restrict__ bw, const float* __restrict__ bb,
    const float* __restrict__ bm, const float* __restrict__ bv,
    const float* __restrict__ pr, float* __restrict__ out) {
  int id = blockIdx.x * 256 + threadIdx.x;  // 96*2304
  int p = id % LT, co = id / LT;
  float acc = 0.f;
  const float* wr = wt + co * CCH;
  for (int ci = 0; ci < CCH; ++ci) acc = fmaf(wr[ci], x[ci * LT + p], acc);
  float s = bw[co] * rsqrtf(bv[co] + 1e-5f);
  float y = (acc - bm[co]) * s + bb[co];
  out[id] = y > 0.f ? y : pr[co] * y;
}

// 3x3 conv (pad 1) + BN + PReLU, 4 output channels per thread
__global__ void __launch_bounds__(256) k_conv1(
    const float* __restrict__ in, const float* __restrict__ wt,
    const float* __restrict__ bw, const float* __restrict__ bb,
    const float* __restrict__ bm, const float* __restrict__ bv,
    const float* __restrict__ pr, float* __restrict__ out) {
  int id = blockIdx.x * 256 + threadIdx.x;  // 24*2304
  int p = id % LT, c0 = id / LT;
  int py = p / HWD, px = p % HWD;
  float a0 = 0.f, a1 = 0.f, a2 = 0.f, a3 = 0.f;
  for (int ci = 0; ci < CCH; ++ci) {
    const float* ip = in + ci * LT;
    #pragma unroll
    for (int dy = -1; dy <= 1; ++dy) {
      int yy = py + dy;
      if (yy < 0 || yy >= HWD) continue;
      #pragma unroll
      for (int dx = -1; dx <= 1; ++dx) {
        int xx2 = px + dx;
        if (xx2 < 0 || xx2 >= HWD) continue;
        float v = ip[yy * HWD + xx2];
        int wb = (ci * 3 + (dy + 1)) * 3 + (dx + 1);
        a0 = fmaf(wt[(c0     ) * CCH * 9 + wb], v, a0);
        a1 = fmaf(wt[(c0 + 24) * CCH * 9 + wb], v, a1);
        a2 = fmaf(wt[(c0 + 48) * CCH * 9 + wb], v, a2);
        a3 = fmaf(wt[(c0 + 72) * CCH * 9 + wb], v, a3);
      }
    }
  }
  float acc[4] = {a0, a1, a2, a3};
  #pragma unroll
  for (int j = 0; j < 4; ++j) {
    int co = c0 + j * 24;
    float s = bw[co] * rsqrtf(bv[co] + 1e-5f);
    float y = (acc[j] - bm[co]) * s + bb[co];
    out[co * LT + p] = y > 0.f ? y : pr[co] * y;
  }
}

// in_proj: xz[e][p] = sum_c W[e][c]*in[c][p]; e<192 -> xx[d][p], e>=192 -> silu(z)[p][d]
__global__ void __launch_bounds__(256) k_inproj(
    const float* __restrict__ in, const float* __restrict__ wt,
    float* __restrict__ xx, float* __restrict__ zsil) {
  int id = blockIdx.x * 256 + threadIdx.x;  // 96*2304
  int p = id % LT, e0 = id / LT;
  float a0 = 0.f, a1 = 0.f, a2 = 0.f, a3 = 0.f;
  for (int c = 0; c < CCH; ++c) {
    float v = in[c * LT + p];
    a0 = fmaf(wt[(e0      ) * CCH + c], v, a0);
    a1 = fmaf(wt[(e0 +  96) * CCH + c], v, a1);
    a2 = fmaf(wt[(e0 + 192) * CCH + c], v, a2);
    a3 = fmaf(wt[(e0 + 288) * CCH + c], v, a3);
  }
  xx[e0 * LT + p]        = a0;
  xx[(e0 + 96) * LT + p] = a1;
  zsil[p * DIM + e0]      = silu_f(a2);
  zsil[p * DIM + e0 + 96] = silu_f(a3);
}

// depthwise 3x3 + bias + SiLU; writes row-major xc AND transposed xcT
__global__ void __launch_bounds__(256) k_dwconv(
    const float* __restrict__ xx, const float* __restrict__ wt,
    const float* __restrict__ bias, float* __restrict__ xc,
    float* __restrict__ xcT) {
  int id = blockIdx.x * 256 + threadIdx.x;  // 192*2304
  int p = id % LT, d = id / LT;
  int py = p / HWD, px = p % HWD;
  float acc = bias[d];
  const float* ip = xx + d * LT;
  #pragma unroll
  for (int dy = -1; dy <= 1; ++dy) {
    int yy = py + dy;
    if (yy < 0 || yy >= HWD) continue;
    #pragma unroll
    for (int dx = -1; dx <= 1; ++dx) {
      int xx2 = px + dx;
      if (xx2 < 0 || xx2 >= HWD) continue;
      acc = fmaf(wt[d * 9 + (dy + 1) * 3 + (dx + 1)], ip[yy * HWD + xx2], acc);
    }
  }
  float v = silu_f(acc);
  xc [d * LT + p] = v;
  xcT[d * LT + px * HWD + py] = v;
}

// x_dbl[k][l][c] = sum_d xs[k,d,l] * xw[k,c,d]; one thread per output.
// grid (144, 10), block (64, 4): lanes = consecutive l (coalesced).
__global__ void __launch_bounds__(256) k_xdbl(
    const float* __restrict__ xc, const float* __restrict__ xcT,
    const float* __restrict__ xw, float* __restrict__ xdbl) {
  int kl = blockIdx.x * 64 + threadIdx.x;  // 0..9215
  int c = blockIdx.y * 4 + threadIdx.y;    // 0..39
  if (c >= 38) return;
  int k = kl / LT, l = kl % LT;
  int ll = (k & 2) ? (LT - 1 - l) : l;
  const float* xp = (k & 1) ? xcT : xc;
  const float* wk = xw + (k * 38 + c) * DIM;
  float acc = 0.f;
  #pragma unroll 8
  for (int d = 0; d < DIM; ++d) acc = fmaf(wk[d], xp[d * LT + ll], acc);
  xdbl[(k * LT + l) * 38 + c] = acc;
}

// dtbuf[k][d][l] = softplus(sum_r xdbl[k][l][r]*dtw[k][d][r] + dtb[k][d])
// block: 256 threads = 64 l x 4 d-groups; 6 dt-inputs per l staged in LDS.
__global__ void __launch_bounds__(256) k_dt(
    const float* __restrict__ xdbl, const float* __restrict__ dtw,
    const float* __restrict__ dtb, float* __restrict__ dtbuf) {
  __shared__ float s_x[64 * 7];  // stride 7: conflict-free
  int bid = blockIdx.x;          // 144 = 4k * 36 tiles
  int k = bid / 36;
  int l0 = (bid % 36) * 64;
  int tid = threadIdx.x;
  for (int i = tid; i < 64 * 6; i += 256) {
    int l = i / 6, r = i % 6;
    s_x[l * 7 + r] = xdbl[(k * LT + l0 + l) * 38 + r];
  }
  __syncthreads();
  int tx = tid & 63, ty = tid >> 6;
  const float* sl = s_x + tx * 7;
  #pragma unroll 4
  for (int j = 0; j < 48; ++j) {
    int d = ty * 48 + j;
    const float* wp = dtw + (k * DIM + d) * 6;
    float a = dtb[k * DIM + d];
    a = fmaf(wp[0], sl[0], a);
    a = fmaf(wp[1], sl[1], a);
    a = fmaf(wp[2], sl[2], a);
    a = fmaf(wp[3], sl[3], a);
    a = fmaf(wp[4], sl[4], a);
    a = fmaf(wp[5], sl[5], a);
    dtbuf[(k * DIM + d) * LT + l0 + tx] = softplus_f(a);
  }
}

// Phase A: per-(k,d,chunk) local scan from h=0.  16 lanes = 16 states.
__global__ void __launch_bounds__(256) k_scanA(
    const float* __restrict__ dtbuf, const float* __restrict__ xc,
    const float* __restrict__ xcT, const float* __restrict__ xdbl,
    const float* __restrict__ Abuf, const float* __restrict__ Ds,
    float* __restrict__ yloc, float* __restrict__ cumdt,
    float* __restrict__ hend) {
  int tid = threadIdx.x;
  int g = blockIdx.x * 16 + (tid >> 4);  // 18432 groups
  int n = tid & 15;
  int c = g % NCHK;
  int t = g / NCHK;
  int d = t % DIM, k = t / DIM;
  float An = Abuf[(k * DIM + d) * NST + n];
  float Dv = Ds[k * DIM + d];
  const float* dtp = dtbuf + (k * DIM + d) * LT;
  const float* xp = ((k & 1) ? xcT : xc) + d * LT;
  float h = 0.f, cum = 0.f;
  int l0 = c * LCHK;
  for (int i = 0; i < LCHK; ++i) {
    int l = l0 + i;
    float dt = dtp[l];
    cum += dt;
    float xv = xp[(k & 2) ? (LT - 1 - l) : l];
    const float* row = xdbl + (k * LT + l) * 38;
    float a = __expf(dt * An);
    h = fmaf(h, a, dt * row[6 + n] * xv);
    float part = h * row[22 + n];
    part += __shfl_xor(part, 1, 16);
    part += __shfl_xor(part, 2, 16);
    part += __shfl_xor(part, 4, 16);
    part += __shfl_xor(part, 8, 16);
    if (n == 0) {
      yloc [(k * LT + l) * DIM + d] = part + Dv * xv;
      cumdt[(k * LT + l) * DIM + d] = cum;
    }
  }
  hend[((k * NCHK + c) * NST + n) * DIM + d] = h;
}

// Phase B: sequential stitch of chunk summaries -> hin (incoming h per chunk)
// id ordered (k,n,d) with d fastest: all loads/stores coalesced.
__global__ void __launch_bounds__(256) k_scanB(
    const float* __restrict__ cumdt, const float* __restrict__ hend,
    const float* __restrict__ A2, float* __restrict__ hin) {
  int id = blockIdx.x * 256 + threadIdx.x;  // 12288 = (k,n,d)
  int d = id % DIM;
  int kn = id / DIM;
  int k = kn / NST;
  float An = A2[id];
  float carry = 0.f;
  for (int c = 0; c < NCHK; ++c) {
    int base = ((k * NCHK + c) * NST + (kn % NST)) * DIM + d;
    hin[base] = carry;
    float dtsum = cumdt[(k * LT + c * LCHK + (LCHK - 1)) * DIM + d];
    carry = __expf(An * dtsum) * carry + hend[base];
  }
}

// Phase C: y += sum_n hin[n] * exp(A_n * cumdt) * C_n   (all d-coalesced)
__global__ void __launch_bounds__(256) k_scanC(
    const float* __restrict__ cumdt, const float* __restrict__ hin,
    const float* __restrict__ A2, const float* __restrict__ xdbl,
    float* __restrict__ yloc) {
  int id = blockIdx.x * 256 + threadIdx.x;  // 4*2304*192, d fastest
  int d = id % DIM;
  int t = id / DIM;
  int l = t % LT, k = t / LT;
  int c = l / LCHK;
  if (c == 0) return;  // hin == 0 for first chunk
  int idx = (k * LT + l) * DIM + d;
  float cum = cumdt[idx];
  const float* hp = hin + (k * NCHK + c) * NST * DIM + d;
  const float* Ap = A2 + k * NST * DIM + d;
  const float* Cp = xdbl + (k * LT + l) * 38 + 22;
  float corr = 0.f;
  #pragma unroll
  for (int n = 0; n < NST; ++n)
    corr = fmaf(hp[n * DIM] * __expf(Ap[n * DIM] * cum), Cp[n], corr);
  yloc[idx] += corr;
}

// Combine 4 directions, LayerNorm over DI, multiply by silu(z).
__global__ void __launch_bounds__(64) k_lncomb(
    const float* __restrict__ yloc, const float* __restrict__ zsil,
    const float* __restrict__ nw, const float* __restrict__ nb,
    float* __restrict__ ynorm) {
  int p = blockIdx.x;
  int lane = threadIdx.x;
  int l1 = (p % HWD) * HWD + p / HWD;
  int l0 = p, l2 = LT - 1 - p, l3 = LT - 1 - l1;
  float vs[3];
  #pragma unroll
  for (int j = 0; j < 3; ++j) {
    int d = lane + j * 64;
    vs[j] = yloc[(0 * LT + l0) * DIM + d]
          + yloc[(1 * LT + l1) * DIM + d]
          + yloc[(2 * LT + l2) * DIM + d]
          + yloc[(3 * LT + l3) * DIM + d];
  }
  float s = vs[0] + vs[1] + vs[2];
  #pragma unroll
  for (int m = 1; m < 64; m <<= 1) s += __shfl_xor(s, m, 64);
  float mu = s * (1.f / DIM);
  float s2 = 0.f;
  #pragma unroll
  for (int j = 0; j < 3; ++j) { float tv = vs[j] - mu; s2 = fmaf(tv, tv, s2); }
  #pragma unroll
  for (int m = 1; m < 64; m <<= 1) s2 += __shfl_xor(s2, m, 64);
  float inv = rsqrtf(s2 * (1.f / DIM) + 1e-5f);
  #pragma unroll
  for (int j = 0; j < 3; ++j) {
    int d = lane + j * 64;
    float yn = (vs[j] - mu) * inv * nw[d] + nb[d];
    ynorm[p * DIM + d] = yn * zsil[p * DIM + d];
  }
}

// out_proj + gamma*ss + residual, 4 output channels per thread
__global__ void __launch_bounds__(256) k_out(
    const float* __restrict__ ynorm, const float* __restrict__ opw,
    const float* __restrict__ res, const float* __restrict__ gamma,
    float* __restrict__ out) {
  int id = blockIdx.x * 256 + threadIdx.x;  // 24*2304
  int p = id % LT, c0 = id / LT;
  const float* yp = ynorm + p * DIM;
  float a0 = 0.f, a1 = 0.f, a2 = 0.f, a3 = 0.f;
  for (int d = 0; d < DIM; ++d) {
    float v = yp[d];
    a0 = fmaf(opw[(c0     ) * DIM + d], v, a0);
    a1 = fmaf(opw[(c0 + 24) * DIM + d], v, a1);
    a2 = fmaf(opw[(c0 + 48) * DIM + d], v, a2);
    a3 = fmaf(opw[(c0 + 72) * DIM + d], v, a3);
  }
  float g = gamma[0];
  out[(c0     ) * LT + p] = fmaf(g, a0, res[(c0     ) * LT + p]);
  out[(c0 + 24) * LT + p] = fmaf(g, a1, res[(c0 + 24) * LT + p]);
  out[(c0 + 48) * LT + p] = fmaf(g, a2, res[(c0 + 48) * LT + p]);
  out[(c0 + 72) * LT + p] = fmaf(g, a3, res[(c0 + 72) * LT + p]);
}

}  // namespace

extern "C" void kernel_launch(void* const* d_in, const int* in_sizes, int n_in,
                              void* d_out, int out_size, void* d_ws, size_t ws_size,
                              hipStream_t stream) {
  (void)in_sizes; (void)n_in; (void)out_size; (void)ws_size;
  const float* x    = (const float*)d_in[0];
  const float* c0w  = (const float*)d_in[1];
  const float* bn0w = (const float*)d_in[2];
  const float* bn0b = (const float*)d_in[3];
  const float* bn0m = (const float*)d_in[4];
  const float* bn0v = (const float*)d_in[5];
  const float* pr0  = (const float*)d_in[6];
  const float* c1w  = (const float*)d_in[7];
  const float* bn1w = (const float*)d_in[8];
  const float* bn1b = (const float*)d_in[9];
  const float* bn1m = (const float*)d_in[10];
  const float* bn1v = (const float*)d_in[11];
  const float* pr1  = (const float*)d_in[12];
  const float* ipw  = (const float*)d_in[13];
  const float* dww  = (const float*)d_in[14];
  const float* dwb  = (const float*)d_in[15];
  const float* xpw  = (const float*)d_in[16];
  const float* dtw  = (const float*)d_in[17];
  const float* dtb  = (const float*)d_in[18];
  const float* alog = (const float*)d_in[19];
  const float* Dsp  = (const float*)d_in[20];
  const float* onw  = (const float*)d_in[21];
  const float* onb  = (const float*)d_in[22];
  const float* opw  = (const float*)d_in[23];
  const float* gam  = (const float*)d_in[24];
  float* out = (float*)d_out;

  // workspace carve (floats); total ~8.47M floats = 33.9 MB (same as R0)
  float* ws    = (float*)d_ws;
  float* out0  = ws;                 // 96*2304   (dead after conv1 -> A2)
  float* out1  = out0  + 221184;     // 96*2304
  float* xxb   = out1  + 221184;     // 192*2304
  float* zsil  = xxb   + 442368;     // 2304*192
  float* xcb   = zsil  + 442368;     // 192*2304
  float* xdbl  = xcb   + 442368;     // 4*2304*38
  float* dtbuf = xdbl  + 350208;     // 4*192*2304
  float* cumdt = dtbuf + 1769472;    // 4*2304*192
  float* yloc  = cumdt + 1769472;    // 4*2304*192
  float* hend  = yloc  + 1769472;    // 4*24*16*192
  float* hin   = hend  + 294912;     // 4*24*16*192
  float* Abuf  = hin   + 294912;     // 4*192*16
  float* ynorm = Abuf  + 12288;      // 2304*192  (doubles as xcT before lncomb)
  float* A2    = out0;               // 12288, aliases out0 (written after conv1)
  float* xcT   = ynorm;              // 192*2304, dead once lncomb writes ynorm

  k_conv0 <<< 864, 256, 0, stream>>>(x, c0w, bn0w, bn0b, bn0m, bn0v, pr0, out0);
  k_conv1 <<< 216, 256, 0, stream>>>(out0, c1w, bn1w, bn1b, bn1m, bn1v, pr1, out1);
  k_abuf  <<<  48, 256, 0, stream>>>(alog, Abuf, A2);   // after conv1 (A2 aliases out0)
  k_inproj<<< 864, 256, 0, stream>>>(out1, ipw, xxb, zsil);
  k_dwconv<<<1728, 256, 0, stream>>>(xxb, dww, dwb, xcb, xcT);
  k_xdbl  <<<dim3(144, 10), dim3(64, 4), 0, stream>>>(xcb, xcT, xpw, xdbl);
  k_dt    <<< 144, 256, 0, stream>>>(xdbl, dtw, dtb, dtbuf);
  k_scanA <<<1152, 256, 0, stream>>>(dtbuf, xcb, xcT, xdbl, Abuf, Dsp, yloc, cumdt, hend);
  k_scanB <<<  48, 256, 0, stream>>>(cumdt, hend, A2, hin);
  k_scanC <<<6912, 256, 0, stream>>>(cumdt, hin, A2, xdbl, yloc);
  k_lncomb<<<2304,  64, 0, stream>>>(yloc, zsil, onw, onb, ynorm);
  k_out   <<< 216, 256, 0, stream>>>(ynorm, opw, out1, gam, out);
}

// Round 3
// 309.536 us; speedup vs baseline: 1.7443x; 1.2849x over previous
//
#include <hip/hip_runtime.h>
#include <math.h>

// SS2D wrapper: conv1x1+BN+PReLU -> conv3x3+BN+PReLU -> SS2D(4-dir selective
// scan) -> gamma*ss + residual.  All fp32.  B=1, C=96, H=W=48, DI=192, N=16,
// R=6, K=4, L=2304.  Scan parallelized via 24-chunk 3-phase decomposition.
// R1: x_dbl/dt output-parallel; xcT for coalesced col-major loads.
// R2: conv1 2-co/thread with blockIdx-derived co (scalar weights) + predicated
//     taps (was 9% occ, 140us); conv0/inproj/out same scalar-weight treatment;
//     lncomb writes transposed ynormT so k_out reads coalesce; scanA 16-wide
//     cooperative dt/x preload + shfl broadcast.

namespace {

constexpr int LT   = 2304;  // H*W
constexpr int HWD  = 48;
constexpr int CCH  = 96;
constexpr int DIM  = 192;
constexpr int NST  = 16;
constexpr int NCHK = 24;    // chunks over L
constexpr int LCHK = 96;    // chunk length (NCHK*LCHK == LT)

__device__ __forceinline__ float silu_f(float v) { return v / (1.f + __expf(-v)); }
__device__ __forceinline__ float softplus_f(float v) {
  return (v > 20.f) ? v : log1pf(__expf(v));
}

// A[k,d,n] = -exp(A_logs); two layouts:
//   Abuf[(k*DIM+d)*NST+n]  (scanA: lane-n consecutive)
//   A2  [(k*NST+n)*DIM+d]  (scanB/C: lane-d consecutive)
__global__ void __launch_bounds__(256) k_abuf(const float* __restrict__ alog,
                                              float* __restrict__ ab,
                                              float* __restrict__ a2) {
  int id = blockIdx.x * 256 + threadIdx.x;  // 12288
  float v = -__expf(alog[id]);
  ab[id] = v;
  int n = id & 15;
  int kd = id >> 4;
  int d = kd % DIM, k = kd / DIM;
  a2[(k * NST + n) * DIM + d] = v;
}

// 1x1 conv + BN + PReLU; co from blockIdx -> scalar weight loads
__global__ void __launch_bounds__(256) k_conv0(
    const float* __restrict__ x, const float* __restrict__ wt,
    const float* __restrict__ bw, const float* __restrict__ bb,
    const float* __restrict__ bm, const float* __restrict__ bv,
    const float* __restrict__ pr, float* __restrict__ out) {
  int bid = blockIdx.x;            // 864 = 96 co x 9 tiles
  int co = bid / 9;
  int p = (bid % 9) * 256 + threadIdx.x;
  float acc = 0.f;
  const float* wr = wt + co * CCH;
  #pragma unroll 4
  for (int ci = 0; ci < CCH; ++ci) acc = fmaf(wr[ci], x[ci * LT + p], acc);
  float s = bw[co] * rsqrtf(bv[co] + 1e-5f);
  float y = (acc - bm[co]) * s + bb[co];
  out[co * LT + p] = y > 0.f ? y : pr[co] * y;
}

// 3x3 conv (pad 1) + BN + PReLU; 2 co/thread, co pair from blockIdx (scalar
// weights), predicated tap loads.
__global__ void __launch_bounds__(256) k_conv1(
    const float* __restrict__ in, const float* __restrict__ wt,
    const float* __restrict__ bw, const float* __restrict__ bb,
    const float* __restrict__ bm, const float* __restrict__ bv,
    const float* __restrict__ pr, float* __restrict__ out) {
  int bid = blockIdx.x;            // 432 = 48 co-pairs x 9 tiles
  int c0 = (bid / 9) * 2;
  int p = (bid % 9) * 256 + threadIdx.x;
  int py = p / HWD, px = p % HWD;
  const float* w0 = wt + (c0    ) * CCH * 9;
  const float* w1 = wt + (c0 + 1) * CCH * 9;
  float a0 = 0.f, a1 = 0.f;
  #pragma unroll 2
  for (int ci = 0; ci < CCH; ++ci) {
    float r[9];
    #pragma unroll
    for (int dy = 0; dy < 3; ++dy) {
      int yy = py + dy - 1;
      bool vy = (unsigned)yy < (unsigned)HWD;
      const float* rp = in + ci * LT + yy * HWD + px;
      r[dy * 3 + 0] = (vy && px != 0)        ? rp[-1] : 0.f;
      r[dy * 3 + 1] = vy                     ? rp[0]  : 0.f;
      r[dy * 3 + 2] = (vy && px != HWD - 1)  ? rp[1]  : 0.f;
    }
    const float* wp0 = w0 + ci * 9;
    const float* wp1 = w1 + ci * 9;
    #pragma unroll
    for (int t = 0; t < 9; ++t) {
      a0 = fmaf(wp0[t], r[t], a0);
      a1 = fmaf(wp1[t], r[t], a1);
    }
  }
  #pragma unroll
  for (int j = 0; j < 2; ++j) {
    int co = c0 + j;
    float acc = j ? a1 : a0;
    float s = bw[co] * rsqrtf(bv[co] + 1e-5f);
    float y = (acc - bm[co]) * s + bb[co];
    out[co * LT + p] = y > 0.f ? y : pr[co] * y;
  }
}

// in_proj; e0 from blockIdx -> scalar weights. 4 outputs/thread.
__global__ void __launch_bounds__(256) k_inproj(
    const float* __restrict__ in, const float* __restrict__ wt,
    float* __restrict__ xx, float* __restrict__ zsil) {
  int bid = blockIdx.x;            // 864 = 96 e0 x 9 tiles
  int e0 = bid / 9;
  int p = (bid % 9) * 256 + threadIdx.x;
  float a0 = 0.f, a1 = 0.f, a2 = 0.f, a3 = 0.f;
  const float* wp0 = wt + (e0      ) * CCH;
  const float* wp1 = wt + (e0 +  96) * CCH;
  const float* wp2 = wt + (e0 + 192) * CCH;
  const float* wp3 = wt + (e0 + 288) * CCH;
  #pragma unroll 4
  for (int c = 0; c < CCH; ++c) {
    float v = in[c * LT + p];
    a0 = fmaf(wp0[c], v, a0);
    a1 = fmaf(wp1[c], v, a1);
    a2 = fmaf(wp2[c], v, a2);
    a3 = fmaf(wp3[c], v, a3);
  }
  xx[e0 * LT + p]        = a0;
  xx[(e0 + 96) * LT + p] = a1;
  zsil[p * DIM + e0]      = silu_f(a2);
  zsil[p * DIM + e0 + 96] = silu_f(a3);
}

// depthwise 3x3 + bias + SiLU; writes row-major xc AND transposed xcT
__global__ void __launch_bounds__(256) k_dwconv(
    const float* __restrict__ xx, const float* __restrict__ wt,
    const float* __restrict__ bias, float* __restrict__ xc,
    float* __restrict__ xcT) {
  int id = blockIdx.x * 256 + threadIdx.x;  // 192*2304
  int p = id % LT, d = id / LT;
  int py = p / HWD, px = p % HWD;
  float acc = bias[d];
  const float* ip = xx + d * LT;
  #pragma unroll
  for (int dy = -1; dy <= 1; ++dy) {
    int yy = py + dy;
    if (yy < 0 || yy >= HWD) continue;
    #pragma unroll
    for (int dx = -1; dx <= 1; ++dx) {
      int xx2 = px + dx;
      if (xx2 < 0 || xx2 >= HWD) continue;
      acc = fmaf(wt[d * 9 + (dy + 1) * 3 + (dx + 1)], ip[yy * HWD + xx2], acc);
    }
  }
  float v = silu_f(acc);
  xc [d * LT + p] = v;
  xcT[d * LT + px * HWD + py] = v;
}

// x_dbl[k][l][c] = sum_d xs[k,d,l] * xw[k,c,d]; one thread per output.
__global__ void __launch_bounds__(256) k_xdbl(
    const float* __restrict__ xc, const float* __restrict__ xcT,
    const float* __restrict__ xw, float* __restrict__ xdbl) {
  int kl = blockIdx.x * 64 + threadIdx.x;  // 0..9215
  int c = blockIdx.y * 4 + threadIdx.y;    // 0..39
  if (c >= 38) return;
  int k = kl / LT, l = kl % LT;
  int ll = (k & 2) ? (LT - 1 - l) : l;
  const float* xp = (k & 1) ? xcT : xc;
  const float* wk = xw + (k * 38 + c) * DIM;
  float acc = 0.f;
  #pragma unroll 8
  for (int d = 0; d < DIM; ++d) acc = fmaf(wk[d], xp[d * LT + ll], acc);
  xdbl[(k * LT + l) * 38 + c] = acc;
}

// dtbuf[k][d][l] = softplus(sum_r xdbl[k][l][r]*dtw[k][d][r] + dtb[k][d])
__global__ void __launch_bounds__(256) k_dt(
    const float* __restrict__ xdbl, const float* __restrict__ dtw,
    const float* __restrict__ dtb, float* __restrict__ dtbuf) {
  __shared__ float s_x[64 * 7];  // stride 7: conflict-free
  int bid = blockIdx.x;          // 144 = 4k * 36 tiles
  int k = bid / 36;
  int l0 = (bid % 36) * 64;
  int tid = threadIdx.x;
  for (int i = tid; i < 64 * 6; i += 256) {
    int l = i / 6, r = i % 6;
    s_x[l * 7 + r] = xdbl[(k * LT + l0 + l) * 38 + r];
  }
  __syncthreads();
  int tx = tid & 63, ty = tid >> 6;
  const float* sl = s_x + tx * 7;
  #pragma unroll 4
  for (int j = 0; j < 48; ++j) {
    int d = ty * 48 + j;
    const float* wp = dtw + (k * DIM + d) * 6;
    float a = dtb[k * DIM + d];
    a = fmaf(wp[0], sl[0], a);
    a = fmaf(wp[1], sl[1], a);
    a = fmaf(wp[2], sl[2], a);
    a = fmaf(wp[3], sl[3], a);
    a = fmaf(wp[4], sl[4], a);
    a = fmaf(wp[5], sl[5], a);
    dtbuf[(k * DIM + d) * LT + l0 + tx] = softplus_f(a);
  }
}

// Phase A: per-(k,d,chunk) local scan from h=0.  16 lanes = 16 states.
// dt/x loaded cooperatively 16-wide then shfl-broadcast (was wave-uniform
// loads: 4 useful dwords per instr).
__global__ void __launch_bounds__(256) k_scanA(
    const float* __restrict__ dtbuf, const float* __restrict__ xc,
    const float* __restrict__ xcT, const float* __restrict__ xdbl,
    const float* __restrict__ Abuf, const float* __restrict__ Ds,
    float* __restrict__ yloc, float* __restrict__ cumdt,
    float* __restrict__ hend) {
  int tid = threadIdx.x;
  int g = blockIdx.x * 16 + (tid >> 4);  // 18432 groups
  int n = tid & 15;
  int c = g % NCHK;
  int t = g / NCHK;
  int d = t % DIM, k = t / DIM;
  float An = Abuf[(k * DIM + d) * NST + n];
  float Dv = Ds[k * DIM + d];
  const float* dtp = dtbuf + (k * DIM + d) * LT;
  const float* xp = ((k & 1) ? xcT : xc) + d * LT;
  float h = 0.f, cum = 0.f;
  int l0 = c * LCHK;
  for (int ib = 0; ib < LCHK; ib += 16) {
    int ln = l0 + ib + n;
    float dtv = dtp[ln];
    float xvv = xp[(k & 2) ? (LT - 1 - ln) : ln];
    #pragma unroll
    for (int j = 0; j < 16; ++j) {
      int l = l0 + ib + j;
      float dt = __shfl(dtv, j, 16);
      float xv = __shfl(xvv, j, 16);
      cum += dt;
      const float* row = xdbl + (k * LT + l) * 38;
      float a = __expf(dt * An);
      h = fmaf(h, a, dt * row[6 + n] * xv);
      float part = h * row[22 + n];
      part += __shfl_xor(part, 1, 16);
      part += __shfl_xor(part, 2, 16);
      part += __shfl_xor(part, 4, 16);
      part += __shfl_xor(part, 8, 16);
      if (n == 0) {
        yloc [(k * LT + l) * DIM + d] = part + Dv * xv;
        cumdt[(k * LT + l) * DIM + d] = cum;
      }
    }
  }
  hend[((k * NCHK + c) * NST + n) * DIM + d] = h;
}

// Phase B: sequential stitch of chunk summaries -> hin (incoming h per chunk)
__global__ void __launch_bounds__(256) k_scanB(
    const float* __restrict__ cumdt, const float* __restrict__ hend,
    const float* __restrict__ A2, float* __restrict__ hin) {
  int id = blockIdx.x * 256 + threadIdx.x;  // 12288 = (k,n,d)
  int d = id % DIM;
  int kn = id / DIM;
  int k = kn / NST;
  float An = A2[id];
  float carry = 0.f;
  for (int c = 0; c < NCHK; ++c) {
    int base = ((k * NCHK + c) * NST + (kn % NST)) * DIM + d;
    hin[base] = carry;
    float dtsum = cumdt[(k * LT + c * LCHK + (LCHK - 1)) * DIM + d];
    carry = __expf(An * dtsum) * carry + hend[base];
  }
}

// Phase C: y += sum_n hin[n] * exp(A_n * cumdt) * C_n   (all d-coalesced)
__global__ void __launch_bounds__(256) k_scanC(
    const float* __restrict__ cumdt, const float* __restrict__ hin,
    const float* __restrict__ A2, const float* __restrict__ xdbl,
    float* __restrict__ yloc) {
  int id = blockIdx.x * 256 + threadIdx.x;  // 4*2304*192, d fastest
  int d = id % DIM;
  int t = id / DIM;
  int l = t % LT, k = t / LT;
  int c = l / LCHK;
  if (c == 0) return;  // hin == 0 for first chunk
  int idx = (k * LT + l) * DIM + d;
  float cum = cumdt[idx];
  const float* hp = hin + (k * NCHK + c) * NST * DIM + d;
  const float* Ap = A2 + k * NST * DIM + d;
  const float* Cp = xdbl + (k * LT + l) * 38 + 22;
  float corr = 0.f;
  #pragma unroll
  for (int n = 0; n < NST; ++n)
    corr = fmaf(hp[n * DIM] * __expf(Ap[n * DIM] * cum), Cp[n], corr);
  yloc[idx] += corr;
}

// Combine 4 directions, LayerNorm over DI, multiply by silu(z).
// Writes TRANSPOSED ynormT[d][p] so k_out reads coalesce.
__global__ void __launch_bounds__(64) k_lncomb(
    const float* __restrict__ yloc, const float* __restrict__ zsil,
    const float* __restrict__ nw, const float* __restrict__ nb,
    float* __restrict__ ynormT) {
  int p = blockIdx.x;
  int lane = threadIdx.x;
  int l1 = (p % HWD) * HWD + p / HWD;
  int l0 = p, l2 = LT - 1 - p, l3 = LT - 1 - l1;
  float vs[3];
  #pragma unroll
  for (int j = 0; j < 3; ++j) {
    int d = lane + j * 64;
    vs[j] = yloc[(0 * LT + l0) * DIM + d]
          + yloc[(1 * LT + l1) * DIM + d]
          + yloc[(2 * LT + l2) * DIM + d]
          + yloc[(3 * LT + l3) * DIM + d];
  }
  float s = vs[0] + vs[1] + vs[2];
  #pragma unroll
  for (int m = 1; m < 64; m <<= 1) s += __shfl_xor(s, m, 64);
  float mu = s * (1.f / DIM);
  float s2 = 0.f;
  #pragma unroll
  for (int j = 0; j < 3; ++j) { float tv = vs[j] - mu; s2 = fmaf(tv, tv, s2); }
  #pragma unroll
  for (int m = 1; m < 64; m <<= 1) s2 += __shfl_xor(s2, m, 64);
  float inv = rsqrtf(s2 * (1.f / DIM) + 1e-5f);
  #pragma unroll
  for (int j = 0; j < 3; ++j) {
    int d = lane + j * 64;
    float yn = (vs[j] - mu) * inv * nw[d] + nb[d];
    ynormT[d * LT + p] = yn * zsil[p * DIM + d];
  }
}

// out_proj + gamma*ss + residual; 2 co/thread, co pair from blockIdx
// (scalar weights), ynormT reads coalesced.
__global__ void __launch_bounds__(256) k_out(
    const float* __restrict__ ynormT, const float* __restrict__ opw,
    const float* __restrict__ res, const float* __restrict__ gamma,
    float* __restrict__ out) {
  int bid = blockIdx.x;            // 432 = 48 co-pairs x 9 tiles
  int c0 = (bid / 9) * 2;
  int p = (bid % 9) * 256 + threadIdx.x;
  const float* w0 = opw + (c0    ) * DIM;
  const float* w1 = opw + (c0 + 1) * DIM;
  float a0 = 0.f, a1 = 0.f;
  #pragma unroll 4
  for (int d = 0; d < DIM; ++d) {
    float v = ynormT[d * LT + p];
    a0 = fmaf(w0[d], v, a0);
    a1 = fmaf(w1[d], v, a1);
  }
  float g = gamma[0];
  out[(c0    ) * LT + p] = fmaf(g, a0, res[(c0    ) * LT + p]);
  out[(c0 + 1) * LT + p] = fmaf(g, a1, res[(c0 + 1) * LT + p]);
}

}  // namespace

extern "C" void kernel_launch(void* const* d_in, const int* in_sizes, int n_in,
                              void* d_out, int out_size, void* d_ws, size_t ws_size,
                              hipStream_t stream) {
  (void)in_sizes; (void)n_in; (void)out_size; (void)ws_size;
  const float* x    = (const float*)d_in[0];
  const float* c0w  = (const float*)d_in[1];
  const float* bn0w = (const float*)d_in[2];
  const float* bn0b = (const float*)d_in[3];
  const float* bn0m = (const float*)d_in[4];
  const float* bn0v = (const float*)d_in[5];
  const float* pr0  = (const float*)d_in[6];
  const float* c1w  = (const float*)d_in[7];
  const float* bn1w = (const float*)d_in[8];
  const float* bn1b = (const float*)d_in[9];
  const float* bn1m = (const float*)d_in[10];
  const float* bn1v = (const float*)d_in[11];
  const float* pr1  = (const float*)d_in[12];
  const float* ipw  = (const float*)d_in[13];
  const float* dww  = (const float*)d_in[14];
  const float* dwb  = (const float*)d_in[15];
  const float* xpw  = (const float*)d_in[16];
  const float* dtw  = (const float*)d_in[17];
  const float* dtb  = (const float*)d_in[18];
  const float* alog = (const float*)d_in[19];
  const float* Dsp  = (const float*)d_in[20];
  const float* onw  = (const float*)d_in[21];
  const float* onb  = (const float*)d_in[22];
  const float* opw  = (const float*)d_in[23];
  const float* gam  = (const float*)d_in[24];
  float* out = (float*)d_out;

  // workspace carve (floats); total ~8.47M floats = 33.9 MB
  float* ws    = (float*)d_ws;
  float* out0  = ws;                 // 96*2304   (dead after conv1 -> A2)
  float* out1  = out0  + 221184;     // 96*2304
  float* xxb   = out1  + 221184;     // 192*2304
  float* zsil  = xxb   + 442368;     // 2304*192
  float* xcb   = zsil  + 442368;     // 192*2304
  float* xdbl  = xcb   + 442368;     // 4*2304*38
  float* dtbuf = xdbl  + 350208;     // 4*192*2304
  float* cumdt = dtbuf + 1769472;    // 4*2304*192
  float* yloc  = cumdt + 1769472;    // 4*2304*192
  float* hend  = yloc  + 1769472;    // 4*24*16*192
  float* hin   = hend  + 294912;     // 4*24*16*192
  float* Abuf  = hin   + 294912;     // 4*192*16
  float* ynormT= Abuf  + 12288;      // 192*2304  (doubles as xcT before lncomb)
  float* A2    = out0;               // 12288, aliases out0 (written after conv1)
  float* xcT   = ynormT;             // 192*2304, dead once lncomb writes ynormT

  k_conv0 <<< 864, 256, 0, stream>>>(x, c0w, bn0w, bn0b, bn0m, bn0v, pr0, out0);
  k_conv1 <<< 432, 256, 0, stream>>>(out0, c1w, bn1w, bn1b, bn1m, bn1v, pr1, out1);
  k_abuf  <<<  48, 256, 0, stream>>>(alog, Abuf, A2);   // after conv1 (A2 aliases out0)
  k_inproj<<< 864, 256, 0, stream>>>(out1, ipw, xxb, zsil);
  k_dwconv<<<1728, 256, 0, stream>>>(xxb, dww, dwb, xcb, xcT);
  k_xdbl  <<<dim3(144, 10), dim3(64, 4), 0, stream>>>(xcb, xcT, xpw, xdbl);
  k_dt    <<< 144, 256, 0, stream>>>(xdbl, dtw, dtb, dtbuf);
  k_scanA <<<1152, 256, 0, stream>>>(dtbuf, xcb, xcT, xdbl, Abuf, Dsp, yloc, cumdt, hend);
  k_scanB <<<  48, 256, 0, stream>>>(cumdt, hend, A2, hin);
  k_scanC <<<6912, 256, 0, stream>>>(cumdt, hin, A2, xdbl, yloc);
  k_lncomb<<<2304,  64, 0, stream>>>(yloc, zsil, onw, onb, ynormT);
  k_out   <<< 432, 256, 0, stream>>>(ynormT, opw, out1, gam, out);
}